// Round 1
// baseline (179.392 us; speedup 1.0000x reference)
//
#include <hip/hip_runtime.h>

// GCN encoder: 2x (dense transform -> symmetric-normalized neighbor aggregation)
// R3: bf16x3 split MFMA GEMMs (no fp32 MFMA on CDNA4), W pre-swizzled.
// R4: aggregation gather tables bf16 -> halved beyond-L2 gather traffic.
// R5 FAILED: cross-thread fence race in ticket scan -> OOB -> abort.
// R6/R7: race-free fusions + atomic-free bucketed CSR build.
// R8 FAILED / R9 REGRESSED: cooperative grid.sync ~77-100 us each on MI355X
//     (8 non-coherent XCD L2s); multi-dispatch wins.
// R10/R12: 6 dispatches (dependency minimum), 170.2 us best.
// R11 REGRESSED: agg+gemm LDS fusion killed occupancy; occupancy > fusion.
// R13 NEUTRAL: persistent grids (block-issue ramp was not the cost).
// R14: fuse agg1+gemm2 per 64-node block via 33 KB LDS fp32 h1 tile.
//     Differs from R11: LDS 64x132 fp32 = 33 KB keeps 4 blocks/CU and the
//     782-block grid is FULLY co-resident (no ramp). Removes the 51.2 MB
//     h1hi/h1lo HBM round-trip and one dispatch (6->5). Numerics identical:
//     same hi/lo split, now computed in-register from the same fp32.

typedef __attribute__((ext_vector_type(8))) short short8;
typedef __attribute__((ext_vector_type(4))) float float4v;

constexpr int PB = 128;    // partition blocks (histogram/scatter chunks)
constexpr int PERS = 2048; // persistent grid for agg2 (8 blocks/CU)
constexpr int LDW = 132;   // fp32 LDS row stride: 528 B, 16B-aligned, 2-way banks

static __device__ __forceinline__ ushort f2bf(float f) {
  union { float f; unsigned u; } c; c.f = f;
  unsigned u = c.u;
  return (ushort)((u + 0x7fffu + ((u >> 16) & 1u)) >> 16);  // RNE
}
static __device__ __forceinline__ float bf2f(ushort h) {
  union { unsigned u; float f; } c; c.u = ((unsigned)h) << 16;
  return c.f;
}
static __device__ __forceinline__ float bfhi(unsigned packed) {
  union { unsigned u; float f; } c; c.u = packed & 0xffff0000u;
  return c.f;
}
static __device__ __forceinline__ float bflo(unsigned packed) {
  union { unsigned u; float f; } c; c.u = packed << 16;
  return c.f;
}

struct MegaParams {
  const float* x;
  const int* src;
  const int* dst;
  const float* W1;
  const float* b1;
  const float* W2;
  const float* b2;
  int N, E, NBK, EPB, GB, NAGG;
  int* cnt_mat;
  int* bases;      // [NBK+1] bucket base offsets (published by scatter kernel)
  unsigned* part;
  int* row_ptr;
  float* dinv;
  int* col;
  ushort* h;
  ushort* h2;
  ushort* w1hi;
  ushort* w1lo;
  ushort* w2hi;
  ushort* w2lo;
  float* out;
};

// W swizzle: one 16x32 B-fragment tile (64 lanes).
// Layout [ktile][ntile][lane][j]: B[k=(lane>>4)*8+j][n=lane&15]
static __device__ __forceinline__ void wswz_tile(const float* __restrict__ W,
                                                 ushort* __restrict__ whi,
                                                 ushort* __restrict__ wlo,
                                                 int M, int tile, int lane) {
  int ntiles = M >> 4;
  int kt = tile / ntiles, nt = tile % ntiles;
  int colg = nt * 16 + (lane & 15);
  int krow = kt * 32 + (lane >> 4) * 8;
  size_t o = ((size_t)tile * 64 + lane) * 8;
#pragma unroll
  for (int j = 0; j < 8; j++) {
    float v = W[(size_t)(krow + j) * M + colg];
    ushort h = f2bf(v);
    whi[o + j] = h;
    wlo[o + j] = f2bf(v - bf2f(h));
  }
}

// ---- K1: bucket histogram (bid<PB) + W swizzles (bid in [PB,PB+12)) ------
__global__ __launch_bounds__(256) void k_g1(MegaParams P) {
  __shared__ int hist[512];
  int bid = blockIdx.x, t = threadIdx.x;
  if (bid >= PB) {
    int tile = (bid - PB) * 4 + (t >> 6);
    int lane = t & 63;
    if (tile < 32) wswz_tile(P.W1, P.w1hi, P.w1lo, 128, tile, lane);
    else           wswz_tile(P.W2, P.w2hi, P.w2lo, 64, tile - 32, lane);
    return;
  }
  for (int k = t; k < P.NBK; k += 256) hist[k] = 0;
  __syncthreads();
  int start = bid * P.EPB;
  int stop = min(P.E, start + P.EPB);
  for (int e = start + t * 4; e < stop; e += 1024) {
    if (e + 4 <= stop) {
      int4 d = *(const int4*)(P.dst + e);
      atomicAdd(&hist[d.x >> 7], 1);
      atomicAdd(&hist[d.y >> 7], 1);
      atomicAdd(&hist[d.z >> 7], 1);
      atomicAdd(&hist[d.w >> 7], 1);
    } else {
      for (int j = e; j < stop; j++) atomicAdd(&hist[P.dst[j] >> 7], 1);
    }
  }
  __syncthreads();
  for (int k = t; k < P.NBK; k += 256) P.cnt_mat[k * PB + bid] = hist[k];
}

// ---- gemm1 block: C[64 rows, 128] = A @ W1, fp32 A split to bf16 hi/lo ----
static __device__ void gemm1_block(int gb, const MegaParams& P) {
  constexpr int K = 128, M = 128, NT = M / 16;
  int t = threadIdx.x;
  int lane = t & 63;
  int wv = t >> 6;
  int quad = lane >> 4, lo16 = lane & 15;
  int rowbase = gb * 64 + wv * 16;
  int arow = rowbase + lo16;
  bool arow_ok = arow < P.N;
  float4v acc[NT];
#pragma unroll
  for (int nt = 0; nt < NT; nt++) acc[nt] = (float4v){0.f, 0.f, 0.f, 0.f};
  for (int kt = 0; kt < 4; kt++) {
    short8 ahi, alo;
    float av[8];
    if (arow_ok) {
      const float* ap = P.x + (size_t)arow * K + kt * 32 + quad * 8;
      float4 a0 = *(const float4*)ap;
      float4 a1 = *(const float4*)(ap + 4);
      av[0] = a0.x; av[1] = a0.y; av[2] = a0.z; av[3] = a0.w;
      av[4] = a1.x; av[5] = a1.y; av[6] = a1.z; av[7] = a1.w;
    } else {
#pragma unroll
      for (int j = 0; j < 8; j++) av[j] = 0.f;
    }
#pragma unroll
    for (int j = 0; j < 8; j++) {
      ushort hh = f2bf(av[j]);
      ahi[j] = (short)hh;
      alo[j] = (short)f2bf(av[j] - bf2f(hh));
    }
    const ushort* ph = P.w1hi + ((size_t)(kt * NT) * 64 + lane) * 8;
    const ushort* pl = P.w1lo + ((size_t)(kt * NT) * 64 + lane) * 8;
#pragma unroll
    for (int nt = 0; nt < NT; nt++) {
      short8 bhi = *(const short8*)(ph + nt * 512);
      short8 blo = *(const short8*)(pl + nt * 512);
      acc[nt] = __builtin_amdgcn_mfma_f32_16x16x32_bf16(ahi, bhi, acc[nt], 0, 0, 0);
      acc[nt] = __builtin_amdgcn_mfma_f32_16x16x32_bf16(alo, bhi, acc[nt], 0, 0, 0);
      acc[nt] = __builtin_amdgcn_mfma_f32_16x16x32_bf16(ahi, blo, acc[nt], 0, 0, 0);
    }
  }
  // D layout (m89-verified): col = lane&15, row = quad*4 + reg
#pragma unroll
  for (int nt = 0; nt < NT; nt++) {
#pragma unroll
    for (int r = 0; r < 4; r++) {
      int row = rowbase + quad * 4 + r;
      if (row < P.N) P.h[(size_t)row * M + nt * 16 + lo16] = f2bf(acc[nt][r]);
    }
  }
}

// ---- K2: partition scatter w/ self-computed prefixes (bid<PB) || gemm1 ----
__global__ __launch_bounds__(256) void k_g2(MegaParams P) {
  __shared__ int buf[256];
  __shared__ int base[512];
  __shared__ int tot[512];
  __shared__ int cur[512];
  int bid = blockIdx.x, t = threadIdx.x;
  if (bid >= PB) {
    gemm1_block(bid - PB, P);
    return;
  }
  for (int k = t; k < P.NBK; k += 256) {
    const int* row = P.cnt_mat + (size_t)k * PB;
    int pre = 0, s = 0;
    for (int b = 0; b < PB; b++) {
      int c = row[b];
      s += c;
      if (b < bid) pre += c;
    }
    tot[k] = s;
    cur[k] = pre;
  }
  __syncthreads();
  {
    int carry = 0;
    for (int b0 = 0; b0 < 512; b0 += 256) {
      int idx = b0 + t;
      int v = (idx < P.NBK) ? tot[idx] : 0;
      buf[t] = v;
      __syncthreads();
      for (int off = 1; off < 256; off <<= 1) {
        int add = (t >= off) ? buf[t - off] : 0;
        __syncthreads();
        buf[t] += add;
        __syncthreads();
      }
      base[idx] = carry + buf[t] - v;
      carry += buf[255];
      __syncthreads();
    }
  }
  for (int k = t; k < P.NBK; k += 256) cur[k] += base[k];
  if (bid == 0)
    for (int k = t; k <= P.NBK; k += 256) P.bases[k] = base[k];
  __syncthreads();
  int start = bid * P.EPB, stop = min(P.E, start + P.EPB);
  for (int e = start + t * 4; e < stop; e += 1024) {
    if (e + 4 <= stop) {
      int4 s = *(const int4*)(P.src + e);
      int4 d = *(const int4*)(P.dst + e);
      int p;
      p = atomicAdd(&cur[d.x >> 7], 1); P.part[p] = (unsigned)s.x | ((unsigned)(d.x & 127) << 25);
      p = atomicAdd(&cur[d.y >> 7], 1); P.part[p] = (unsigned)s.y | ((unsigned)(d.y & 127) << 25);
      p = atomicAdd(&cur[d.z >> 7], 1); P.part[p] = (unsigned)s.z | ((unsigned)(d.z & 127) << 25);
      p = atomicAdd(&cur[d.w >> 7], 1); P.part[p] = (unsigned)s.w | ((unsigned)(d.w & 127) << 25);
    } else {
      for (int j = e; j < stop; j++) {
        int p2 = atomicAdd(&cur[P.dst[j] >> 7], 1);
        P.part[p2] = (unsigned)P.src[j] | ((unsigned)(P.dst[j] & 127) << 25);
      }
    }
  }
}

// ---- K3: per-bucket local CSR (LDS count/scan/place); bases from K2 -------
__global__ __launch_bounds__(256) void k_g3(MegaParams P) {
  __shared__ int buf[256];
  __shared__ int cnt[128];
  __shared__ int cur[128];
  int bid = blockIdx.x, t = threadIdx.x;
  int beg = P.bases[bid], end = P.bases[bid + 1];
  if (t < 128) cnt[t] = 0;
  __syncthreads();
  for (int e = beg + t; e < end; e += 256) atomicAdd(&cnt[P.part[e] >> 25], 1);
  __syncthreads();
  int v = (t < 128) ? cnt[t] : 0;
  buf[t] = v;
  __syncthreads();
#pragma unroll
  for (int off = 1; off < 256; off <<= 1) {
    int add = (t >= off) ? buf[t - off] : 0;
    __syncthreads();
    buf[t] += add;
    __syncthreads();
  }
  if (t < 128) {
    int excl = buf[t] - v;
    cur[t] = beg + excl;
    int node = bid * 128 + t;
    if (node < P.N) {
      P.row_ptr[node] = beg + excl;
      P.dinv[node] = rsqrtf((float)(v + 1));  // +1 self loop
    }
  }
  if (bid == 0 && t == 0) P.row_ptr[P.N] = P.E;
  __syncthreads();
  for (int e = beg + t; e < end; e += 256) {
    unsigned p = P.part[e];
    int pos = atomicAdd(&cur[p >> 25], 1);
    P.col[pos] = (int)(p & 0x01FFFFFFu);
  }
}

// ---- K4: FUSED agg1(+bias,relu) -> LDS fp32 tile -> gemm2 -> h2 (bf16) ----
// One 256-thread block owns 64 consecutive nodes. Wave wv aggregates its 16
// nodes (all 64 lanes across 128 ch, 2 ch/lane) into the LDS h1 tile, then
// after one barrier runs the gemm2 MFMA phase on those same 16 rows.
// LDS 64x132 fp32 = 33 KB -> 4 blocks/CU; 782 blocks all co-resident.
__global__ __launch_bounds__(256) void k_g4(MegaParams P) {
  __shared__ float h1t[64 * LDW];
  int b = blockIdx.x;
  int t = threadIdx.x;
  int lane = t & 63, wv = t >> 6;
  int v0 = b * 64 + wv * 16;
  // prefetch this wave's row_ptr[v0..v0+16] and dinv[v0..v0+15] across lanes
  int rp = 0;
  float dvl = 0.f;
  if (lane < 17) {
    int vv = v0 + lane;
    rp = (vv <= P.N) ? P.row_ptr[vv] : P.E;
  }
  if (lane < 16) {
    int vv = v0 + lane;
    dvl = (vv < P.N) ? P.dinv[vv] : 0.f;
  }
#pragma unroll 1
  for (int i = 0; i < 16; i++) {
    int rl = wv * 16 + i;
    int v = v0 + i;
    float acc0 = 0.f, acc1 = 0.f;
    if (v < P.N) {
      float dv = __shfl(dvl, i);
      int beg = __shfl(rp, i), end = __shfl(rp, i + 1);
      unsigned su = *(const unsigned*)(P.h + (size_t)v * 128 + lane * 2);
      acc0 = dv * bflo(su);  // self loop (weight dv)
      acc1 = dv * bfhi(su);
      for (int base = beg; base < end; base += 64) {
        int m = end - base;
        if (m > 64) m = 64;
        int sl = 0;
        float wl = 0.f;
        if (lane < m) {
          sl = P.col[base + lane];
          wl = P.dinv[sl];
        }
        int j = 0;
        for (; j + 8 <= m; j += 8) {
          int s[8]; float wq[8]; unsigned u[8];
#pragma unroll
          for (int q = 0; q < 8; q++) { s[q] = __shfl(sl, j + q); wq[q] = __shfl(wl, j + q); }
#pragma unroll
          for (int q = 0; q < 8; q++) u[q] = *(const unsigned*)(P.h + (size_t)s[q] * 128 + lane * 2);
#pragma unroll
          for (int q = 0; q < 8; q++) {
            acc0 = fmaf(wq[q], bflo(u[q]), acc0);
            acc1 = fmaf(wq[q], bfhi(u[q]), acc1);
          }
        }
        for (; j + 4 <= m; j += 4) {
          int s[4]; float wq[4]; unsigned u[4];
#pragma unroll
          for (int q = 0; q < 4; q++) { s[q] = __shfl(sl, j + q); wq[q] = __shfl(wl, j + q); }
#pragma unroll
          for (int q = 0; q < 4; q++) u[q] = *(const unsigned*)(P.h + (size_t)s[q] * 128 + lane * 2);
#pragma unroll
          for (int q = 0; q < 4; q++) {
            acc0 = fmaf(wq[q], bflo(u[q]), acc0);
            acc1 = fmaf(wq[q], bfhi(u[q]), acc1);
          }
        }
        for (; j < m; j++) {
          int s = __shfl(sl, j);
          float ww = __shfl(wl, j);
          unsigned u = *(const unsigned*)(P.h + (size_t)s * 128 + lane * 2);
          acc0 = fmaf(ww, bflo(u), acc0);
          acc1 = fmaf(ww, bfhi(u), acc1);
        }
      }
      acc0 = fmaf(dv, acc0, P.b1[lane * 2 + 0]);
      acc1 = fmaf(dv, acc1, P.b1[lane * 2 + 1]);
      acc0 = fmaxf(acc0, 0.f);
      acc1 = fmaxf(acc1, 0.f);
    }
    *(float2*)&h1t[rl * LDW + lane * 2] = make_float2(acc0, acc1);
  }
  __syncthreads();
  // ---- gemm2 phase: A = LDS h1 rows (fp32 -> bf16 hi/lo), B = W2 swizzles
  constexpr int NT = 4;  // 64 output cols / 16
  int quad = lane >> 4, lo16 = lane & 15;
  float4v acc[NT];
#pragma unroll
  for (int nt = 0; nt < NT; nt++) acc[nt] = (float4v){0.f, 0.f, 0.f, 0.f};
  for (int kt = 0; kt < 4; kt++) {
    const float* ap = &h1t[(wv * 16 + lo16) * LDW + kt * 32 + quad * 8];
    float4 a0 = *(const float4*)ap;
    float4 a1 = *(const float4*)(ap + 4);
    float av[8];
    av[0] = a0.x; av[1] = a0.y; av[2] = a0.z; av[3] = a0.w;
    av[4] = a1.x; av[5] = a1.y; av[6] = a1.z; av[7] = a1.w;
    short8 ahi, alo;
#pragma unroll
    for (int j = 0; j < 8; j++) {
      ushort hh = f2bf(av[j]);
      ahi[j] = (short)hh;
      alo[j] = (short)f2bf(av[j] - bf2f(hh));
    }
    const ushort* ph = P.w2hi + ((size_t)(kt * NT) * 64 + lane) * 8;
    const ushort* pl = P.w2lo + ((size_t)(kt * NT) * 64 + lane) * 8;
#pragma unroll
    for (int nt = 0; nt < NT; nt++) {
      short8 bhi = *(const short8*)(ph + nt * 512);
      short8 blo = *(const short8*)(pl + nt * 512);
      acc[nt] = __builtin_amdgcn_mfma_f32_16x16x32_bf16(ahi, bhi, acc[nt], 0, 0, 0);
      acc[nt] = __builtin_amdgcn_mfma_f32_16x16x32_bf16(alo, bhi, acc[nt], 0, 0, 0);
      acc[nt] = __builtin_amdgcn_mfma_f32_16x16x32_bf16(ahi, blo, acc[nt], 0, 0, 0);
    }
  }
#pragma unroll
  for (int nt = 0; nt < NT; nt++) {
#pragma unroll
    for (int r = 0; r < 4; r++) {
      int row = b * 64 + wv * 16 + quad * 4 + r;
      if (row < P.N) P.h2[(size_t)row * 64 + nt * 16 + lo16] = f2bf(acc[nt][r]);
    }
  }
}

// ---- aggregation layer 2: one wave per node, 64 ch across lanes ----
static __device__ void agg2_block(int vb, const MegaParams& P) {
  int lane = threadIdx.x & 63;
  int v = vb * 4 + (threadIdx.x >> 6);
  if (v >= P.N) return;
  float dv = P.dinv[v];
  float acc0 = dv * bf2f(P.h2[(size_t)v * 64 + lane]);  // self loop
  int beg = P.row_ptr[v], end = P.row_ptr[v + 1];
  for (int base = beg; base < end; base += 64) {
    int m = end - base;
    if (m > 64) m = 64;
    int sl = 0;
    float wl = 0.f;
    if (lane < m) {
      sl = P.col[base + lane];
      wl = P.dinv[sl];
    }
    int j = 0;
    for (; j + 8 <= m; j += 8) {
      int s[8]; float wq[8]; ushort u[8];
#pragma unroll
      for (int q = 0; q < 8; q++) { s[q] = __shfl(sl, j + q); wq[q] = __shfl(wl, j + q); }
#pragma unroll
      for (int q = 0; q < 8; q++) u[q] = P.h2[(size_t)s[q] * 64 + lane];
#pragma unroll
      for (int q = 0; q < 8; q++) acc0 = fmaf(wq[q], bf2f(u[q]), acc0);
    }
    for (; j + 4 <= m; j += 4) {
      int s[4]; float wq[4]; ushort u[4];
#pragma unroll
      for (int q = 0; q < 4; q++) { s[q] = __shfl(sl, j + q); wq[q] = __shfl(wl, j + q); }
#pragma unroll
      for (int q = 0; q < 4; q++) u[q] = P.h2[(size_t)s[q] * 64 + lane];
#pragma unroll
      for (int q = 0; q < 4; q++) acc0 = fmaf(wq[q], bf2f(u[q]), acc0);
    }
    for (; j < m; j++) {
      int s = __shfl(sl, j);
      float ww = __shfl(wl, j);
      acc0 = fmaf(ww, bf2f(P.h2[(size_t)s * 64 + lane]), acc0);
    }
  }
  float r0 = fmaf(dv, acc0, P.b2[lane]);
  P.out[(size_t)v * 64 + lane] = r0;
}

__global__ __launch_bounds__(256) void k_g5(MegaParams P) {
  for (int vb = blockIdx.x; vb < P.NAGG; vb += gridDim.x) agg2_block(vb, P);
}

extern "C" void kernel_launch(void* const* d_in, const int* in_sizes, int n_in,
                              void* d_out, int out_size, void* d_ws, size_t ws_size,
                              hipStream_t stream) {
  MegaParams P;
  P.x  = (const float*)d_in[0];
  const int* ei = (const int*)d_in[1];
  P.W1 = (const float*)d_in[2];
  P.b1 = (const float*)d_in[3];
  P.W2 = (const float*)d_in[4];
  P.b2 = (const float*)d_in[5];
  P.N = in_sizes[0] / 128;
  P.E = in_sizes[1] / 2;
  P.src = ei;
  P.dst = ei + P.E;
  P.NBK = (P.N + 127) / 128;                   // 391; must be <= 511
  P.EPB = ((P.E + PB - 1) / PB + 3) & ~3;      // edges per partition block, x4
  P.GB = (P.N + 63) / 64;                      // 782
  P.NAGG = (P.N + 3) / 4;                      // 12500

  auto al = [](size_t v) { return (v + 255) & ~(size_t)255; };
  char* w = (char*)d_ws;
  P.cnt_mat = (int*)w;      w += al((size_t)P.NBK * PB * 4);
  P.bases   = (int*)w;      w += al((size_t)(P.NBK + 1) * 4);
  P.part    = (unsigned*)w; w += al((size_t)P.E * 4);
  P.row_ptr = (int*)w;      w += al((size_t)(P.N + 1) * 4);
  P.dinv    = (float*)w;    w += al((size_t)P.N * 4);
  P.col     = (int*)w;      w += al((size_t)P.E * 4);
  P.h       = (ushort*)w;   w += al((size_t)P.N * 128 * 2);
  P.h2      = (ushort*)w;   w += al((size_t)P.N * 64 * 2);
  P.w1hi    = (ushort*)w;   w += al((size_t)128 * 128 * 2);
  P.w1lo    = (ushort*)w;   w += al((size_t)128 * 128 * 2);
  P.w2hi    = (ushort*)w;   w += al((size_t)128 * 64 * 2);
  P.w2lo    = (ushort*)w;   w += al((size_t)128 * 64 * 2);
  P.out = (float*)d_out;

  k_g1<<<PB + 12, 256, 0, stream>>>(P);
  k_g2<<<PB + P.GB, 256, 0, stream>>>(P);
  k_g3<<<P.NBK, 256, 0, stream>>>(P);
  k_g4<<<P.GB, 256, 0, stream>>>(P);   // fused agg1+gemm2
  k_g5<<<PERS, 256, 0, stream>>>(P);   // agg2
}